// Round 16
// baseline (556.317 us; speedup 1.0000x reference)
//
#include <hip/hip_runtime.h>
#include <math.h>

#define HID 256
#define NF 128
#define NGAUSS 100
#define NBLK 6
#define NGRAPH 64
#define CUTOFF_F 10.0f
#define T_TAB 8192
#define PSLICE 8

typedef __attribute__((ext_vector_type(8))) short bf16x8;
typedef __attribute__((ext_vector_type(4))) float f32x4;

__device__ __forceinline__ float ssp(float x) {
    return fmaxf(x, 0.0f) + log1pf(expf(-fabsf(x))) - 0.69314718056f;
}
__device__ __forceinline__ short f2bf(float f) {
    unsigned u = __float_as_uint(f);
    u = u + 0x7fffu + ((u >> 16) & 1u);
    return (short)(u >> 16);
}
__device__ __forceinline__ float bf2f(unsigned s) {
    return __uint_as_float(s << 16);
}

// All 5 weight transposes in one launch: grid.z selects the segment.
__global__ __launch_bounds__(256) void prep_weights(
        const float* __restrict__ W1s,   short* __restrict__ W1Tb,
        const float* __restrict__ W2s,   short* __restrict__ W2Tb,
        const float* __restrict__ lin1Ws, short* __restrict__ lin1T,
        const float* __restrict__ lin2Ws, short* __restrict__ W2T,
        const float* __restrict__ linWs,  short* __restrict__ W3T)
{
    const float* in; short* out; int Ks, Kp, C;
    switch (blockIdx.z) {
        case 0: in = W1s;    out = W1Tb;  Ks = NGAUSS; Kp = NF;  C = NF;  break;
        case 1: in = W2s;    out = W2Tb;  Ks = NF;     Kp = NF;  C = NF;  break;
        case 2: in = lin1Ws; out = lin1T; Ks = HID;    Kp = HID; C = NF;  break;
        case 3: in = lin2Ws; out = W2T;   Ks = NF;     Kp = NF;  C = HID; break;
        default: in = linWs; out = W3T;   Ks = HID;    Kp = HID; C = HID; break;
    }
    int i = blockIdx.y;
    int idx = blockIdx.x * 256 + threadIdx.x;
    if (idx >= Kp * C) return;
    int k = idx / C, c = idx % C;
    out[((size_t)i * C + c) * Kp + k] =
        (k < Ks) ? f2bf(in[((size_t)i * Ks + k) * C + c]) : (short)0;
}

// Wtab[i][t][c] = (ssp(gauss(d_t) @ W1_i + b1_i) @ W2_i + b2_i)[c] via MFMA.
// Layout: [i][(T_TAB+1)][NF]; row T_TAB = zero sink (gated edges).
__global__ __launch_bounds__(256) void build_table_mfma(
        const short* __restrict__ W1T, const float* __restrict__ b1s,
        const short* __restrict__ W2T, const float* __restrict__ b2s,
        short* __restrict__ Wtab)
{
    __shared__ short Gs[32 * NF];
    __shared__ short Hs[32 * NF];
    char* gb = (char*)Gs;
    char* hb = (char*)Hs;
    const int i = blockIdx.y;
    const int r0 = blockIdx.x * 32;
    const int wv = threadIdx.x >> 6, lane = threadIdx.x & 63;
    const int lrow = lane & 15, lgrp = lane >> 4;

    const float delta = CUTOFF_F / 99.0f;
    const float coeff = -0.5f / (delta * delta);
    for (int idx = threadIdx.x; idx < 32 * NF; idx += 256) {
        int row = idx >> 7, k = idx & 127;
        float d = (float)(r0 + row) * (CUTOFF_F / (float)(T_TAB - 1));
        float x = d - (float)k * delta;
        float v = (k < NGAUSS) ? expf(coeff * x * x) : 0.0f;
        int byte = idx * 2;
        byte ^= (row & 7) << 4;
        *(short*)(gb + byte) = f2bf(v);
    }
    __syncthreads();

    f32x4 zero = {0.0f, 0.0f, 0.0f, 0.0f};
    f32x4 c1[2][2] = {{zero, zero}, {zero, zero}};
    for (int s = 0; s < 4; ++s) {
        bf16x8 a[2], b[2];
        #pragma unroll
        for (int m = 0; m < 2; ++m) {
            int row = m * 16 + lrow;
            int byte = (row * NF + s * 32 + lgrp * 8) * 2;
            byte ^= (row & 7) << 4;
            a[m] = *(const bf16x8*)(gb + byte);
        }
        #pragma unroll
        for (int n = 0; n < 2; ++n) {
            int col = wv * 32 + n * 16 + lrow;
            b[n] = *(const bf16x8*)(W1T + ((size_t)i * NF + col) * NF + s * 32 + lgrp * 8);
        }
        #pragma unroll
        for (int m = 0; m < 2; ++m)
            #pragma unroll
            for (int n = 0; n < 2; ++n)
                c1[m][n] = __builtin_amdgcn_mfma_f32_16x16x32_bf16(a[m], b[n], c1[m][n], 0, 0, 0);
    }
    #pragma unroll
    for (int m = 0; m < 2; ++m)
        #pragma unroll
        for (int n = 0; n < 2; ++n) {
            int col = wv * 32 + n * 16 + lrow;
            float bb = b1s[i * NF + col];
            #pragma unroll
            for (int j = 0; j < 4; ++j) {
                int row = m * 16 + lgrp * 4 + j;
                int byte = (row * NF + col) * 2;
                byte ^= (row & 7) << 4;
                *(short*)(hb + byte) = f2bf(ssp(c1[m][n][j] + bb));
            }
        }
    __syncthreads();

    f32x4 c2[2][2] = {{zero, zero}, {zero, zero}};
    for (int s = 0; s < 4; ++s) {
        bf16x8 a[2], b[2];
        #pragma unroll
        for (int m = 0; m < 2; ++m) {
            int row = m * 16 + lrow;
            int byte = (row * NF + s * 32 + lgrp * 8) * 2;
            byte ^= (row & 7) << 4;
            a[m] = *(const bf16x8*)(hb + byte);
        }
        #pragma unroll
        for (int n = 0; n < 2; ++n) {
            int col = wv * 32 + n * 16 + lrow;
            b[n] = *(const bf16x8*)(W2T + ((size_t)i * NF + col) * NF + s * 32 + lgrp * 8);
        }
        #pragma unroll
        for (int m = 0; m < 2; ++m)
            #pragma unroll
            for (int n = 0; n < 2; ++n)
                c2[m][n] = __builtin_amdgcn_mfma_f32_16x16x32_bf16(a[m], b[n], c2[m][n], 0, 0, 0);
    }
    #pragma unroll
    for (int m = 0; m < 2; ++m)
        #pragma unroll
        for (int n = 0; n < 2; ++n) {
            int col = wv * 32 + n * 16 + lrow;
            float bb = b2s[i * NF + col];
            #pragma unroll
            for (int j = 0; j < 4; ++j) {
                int t = r0 + m * 16 + lgrp * 4 + j;
                Wtab[((size_t)i * (T_TAB + 1) + t) * NF + col] = f2bf(c2[m][n][j] + bb);
            }
        }
}

// zero the sink row (index T_TAB) of each interaction block's table
__global__ __launch_bounds__(128) void zero_sink(short* __restrict__ Wtab)
{
    Wtab[((size_t)blockIdx.x * (T_TAB + 1) + T_TAB) * NF + threadIdx.x] = 0;
}

__global__ __launch_bounds__(256) void embed_k(
        const float* __restrict__ emb, const int* __restrict__ types,
        float* __restrict__ h, int N)
{
    int gid = blockIdx.x * 256 + threadIdx.x;
    if (gid >= N * HID) return;
    int n = gid >> 8, c = gid & (HID - 1);
    h[gid] = emb[(size_t)types[n] * HID + c];
}

// ---------------- CSR build ----------------
__global__ __launch_bounds__(256) void hist_k(
        const int* __restrict__ dst, int* __restrict__ hist, int E)
{
    int e = blockIdx.x * 256 + threadIdx.x;
    if (e < E) atomicAdd(&hist[dst[e]], 1);
}

__global__ __launch_bounds__(1024) void scan_k(
        const int* __restrict__ in, int* __restrict__ out, int n)
{
    __shared__ int wsum[16];
    __shared__ int carry_s;
    const int tid = threadIdx.x, lane = tid & 63, w = tid >> 6;
    if (tid == 0) carry_s = 0;
    __syncthreads();
    for (int base = 0; base < n; base += 1024) {
        int i = base + tid;
        int v = (i < n) ? in[i] : 0;
        int s = v;
        #pragma unroll
        for (int d = 1; d < 64; d <<= 1) {
            int t = __shfl_up(s, d);
            if (lane >= d) s += t;
        }
        if (lane == 63) wsum[w] = s;
        __syncthreads();
        if (w == 0 && lane < 16) {
            int ws = wsum[lane];
            #pragma unroll
            for (int d = 1; d < 16; d <<= 1) {
                int t = __shfl_up(ws, d);
                if (lane >= d) ws += t;
            }
            wsum[lane] = ws;
        }
        __syncthreads();
        int carry = carry_s;
        if (i < n) out[i] = carry + (w ? wsum[w - 1] : 0) + s - v;
        __syncthreads();
        if (tid == 1023) carry_s = carry + wsum[15];
        __syncthreads();
    }
    if (threadIdx.x == 0) out[n] = carry_s;
}

// packed (i0<<32 | src); i0 = nearest table index (precomputed),
// gated edges -> i0 = T_TAB (zero sink row).
__global__ __launch_bounds__(256) void scatter_k(
        const int* __restrict__ src, const int* __restrict__ dst,
        const float* __restrict__ elen, const int* __restrict__ off,
        int* __restrict__ cursor, unsigned long long* __restrict__ csr_pk, int E)
{
    int e = blockIdx.x * 256 + threadIdx.x;
    if (e >= E) return;
    int t = dst[e];
    int pos = off[t] + atomicAdd(&cursor[t], 1);
    float d = elen[e];
    float u = d * ((float)(T_TAB - 1) / CUTOFF_F);
    int i0 = (int)(fminf(fmaxf(u, 0.0f), (float)(T_TAB - 1)) + 0.5f);
    if (i0 > T_TAB - 1) i0 = T_TAB - 1;
    if (d > CUTOFF_F) i0 = T_TAB;   // zero sink
    csr_pk[pos] = ((unsigned long long)(unsigned)i0 << 32) | (unsigned)src[e];
}

// one-time canonical sort of each CSR row: scatter order varies per call,
// sorted content does not -> downstream accumulation is bit-deterministic.
__global__ __launch_bounds__(256) void sort_k(
        const int* __restrict__ off, unsigned long long* __restrict__ csr_pk, int N)
{
    const int node = (blockIdx.x * 256 + threadIdx.x) >> 6;
    const int lane = threadIdx.x & 63;
    if (node >= N) return;
    const int beg = off[node], end = off[node + 1];
    const int deg = end - beg;
    if (deg <= 1) return;
    if (deg <= 128) {
        const unsigned long long PAD = ~0ull;
        unsigned long long v0 = (lane < deg) ? csr_pk[beg + lane] : PAD;
        unsigned long long v1 = (64 + lane < deg) ? csr_pk[beg + 64 + lane] : PAD;
        if (deg > 64) {
            for (int size = 2; size <= 128; size <<= 1)
                for (int stride = size >> 1; stride > 0; stride >>= 1) {
                    if (stride == 64) {
                        unsigned long long lo = v0 < v1 ? v0 : v1;
                        unsigned long long hi = v0 < v1 ? v1 : v0;
                        v0 = lo; v1 = hi;
                    } else {
                        unsigned long long p0 = __shfl_xor(v0, stride);
                        unsigned long long p1 = __shfl_xor(v1, stride);
                        bool up = (lane & stride) != 0;
                        bool d0 = ((lane & size) == 0);
                        bool d1 = (((lane + 64) & size) == 0);
                        v0 = (up ^ d0) ? (v0 < p0 ? v0 : p0) : (v0 > p0 ? v0 : p0);
                        v1 = (up ^ d1) ? (v1 < p1 ? v1 : p1) : (v1 > p1 ? v1 : p1);
                    }
                }
            if (lane < deg) csr_pk[beg + lane] = v0;
            if (64 + lane < deg) csr_pk[beg + 64 + lane] = v1;
        } else {
            for (int size = 2; size <= 64; size <<= 1)
                for (int stride = size >> 1; stride > 0; stride >>= 1) {
                    unsigned long long p0 = __shfl_xor(v0, stride);
                    bool up = (lane & stride) != 0;
                    bool d0 = ((lane & size) == 0);
                    v0 = (up ^ d0) ? (v0 < p0 ? v0 : p0) : (v0 > p0 ? v0 : p0);
                }
            if (lane < deg) csr_pk[beg + lane] = v0;
        }
    } else if (lane == 0) {
        for (int a = beg + 1; a < end; ++a) {
            unsigned long long key = csr_pk[a];
            int b = a - 1;
            while (b >= beg && csr_pk[b] > key) { csr_pk[b + 1] = csr_pk[b]; --b; }
            csr_pk[b + 1] = key;
        }
    }
}

// ---------------- per-block kernels ----------------

// xf = bf16(h @ lin1W)  (block 0 only; later blocks fused into update_k)
__global__ __launch_bounds__(256) void lin1_k(
        const float* __restrict__ h, const short* __restrict__ lin1T,
        short* __restrict__ xf, int N)
{
    const int wv = threadIdx.x >> 6, lane = threadIdx.x & 63;
    const int lrow = lane & 15, lgrp = lane >> 4;
    const int wrow = wv >> 1, wcol = wv & 1;
    const int r0 = blockIdx.x * 64 + wrow * 32;

    f32x4 zero = {0.0f, 0.0f, 0.0f, 0.0f};
    f32x4 c[2][4] = {{zero, zero, zero, zero}, {zero, zero, zero, zero}};

    for (int s = 0; s < 8; ++s) {
        bf16x8 a[2], b[4];
        #pragma unroll
        for (int m = 0; m < 2; ++m) {
            int row = r0 + m * 16 + lrow;
            if (row >= N) row = N - 1;
            const float* hp = h + (size_t)row * HID + s * 32 + lgrp * 8;
            float4 p0 = *(const float4*)hp;
            float4 p1 = *(const float4*)(hp + 4);
            bf16x8 t;
            t[0] = f2bf(p0.x); t[1] = f2bf(p0.y); t[2] = f2bf(p0.z); t[3] = f2bf(p0.w);
            t[4] = f2bf(p1.x); t[5] = f2bf(p1.y); t[6] = f2bf(p1.z); t[7] = f2bf(p1.w);
            a[m] = t;
        }
        #pragma unroll
        for (int n = 0; n < 4; ++n) {
            int col = wcol * 64 + n * 16 + lrow;
            b[n] = *(const bf16x8*)(lin1T + (size_t)col * HID + s * 32 + lgrp * 8);
        }
        #pragma unroll
        for (int m = 0; m < 2; ++m)
            #pragma unroll
            for (int n = 0; n < 4; ++n)
                c[m][n] = __builtin_amdgcn_mfma_f32_16x16x32_bf16(a[m], b[n], c[m][n], 0, 0, 0);
    }
    #pragma unroll
    for (int m = 0; m < 2; ++m)
        #pragma unroll
        for (int n = 0; n < 4; ++n) {
            int col = wcol * 64 + n * 16 + lrow;
            #pragma unroll
            for (int j = 0; j < 4; ++j) {
                int row = r0 + m * 16 + lgrp * 4 + j;
                if (row < N) xf[(size_t)row * NF + col] = f2bf(c[m][n][j]);
            }
        }
}

// one wave per dst node; sorted keys carry precomputed nearest table index ->
// per edge: 2 loads + 4 unpacks + 2 FMA. 8-wide gather groups.
__global__ __launch_bounds__(256) void agg_k(
        const short* __restrict__ xf, const short* __restrict__ wt,
        const int* __restrict__ off, const unsigned long long* __restrict__ csr_pk,
        short* __restrict__ agg, int N)
{
    const int node = (blockIdx.x * 256 + threadIdx.x) >> 6;
    const int lane = threadIdx.x & 63;
    if (node >= N) return;
    const int beg = __builtin_amdgcn_readfirstlane(off[node]);
    const int end = __builtin_amdgcn_readfirstlane(off[node + 1]);
    float a0 = 0.0f, a1 = 0.0f;

    int k = beg;
    for (; k + 8 <= end; k += 8) {
        unsigned long long pk[8];
        #pragma unroll
        for (int q = 0; q < 8; ++q) pk[q] = csr_pk[k + q];
        unsigned wv[8], xv[8];
        #pragma unroll
        for (int q = 0; q < 8; ++q) {
            int i0 = (int)(pk[q] >> 32);
            int s  = (int)(unsigned)pk[q];
            wv[q] = *(const unsigned*)(wt + (size_t)i0 * NF + 2 * lane);
            xv[q] = *(const unsigned*)(xf + (size_t)s * NF + 2 * lane);
        }
        #pragma unroll
        for (int q = 0; q < 8; ++q) {
            float wa = bf2f(wv[q] & 0xffffu), wb = bf2f(wv[q] >> 16);
            float xa = bf2f(xv[q] & 0xffffu), xb = bf2f(xv[q] >> 16);
            a0 = fmaf(xa, wa, a0);
            a1 = fmaf(xb, wb, a1);
        }
    }
    if (k < end) {
        const int rem = end - k;
        unsigned long long pk[8];
        #pragma unroll
        for (int q = 0; q < 8; ++q) {
            int kk = k + q < end ? k + q : end - 1;
            pk[q] = csr_pk[kk];
        }
        unsigned wv[8], xv[8];
        #pragma unroll
        for (int q = 0; q < 8; ++q) {
            int i0 = (int)(pk[q] >> 32);
            int s  = (int)(unsigned)pk[q];
            wv[q] = *(const unsigned*)(wt + (size_t)i0 * NF + 2 * lane);
            xv[q] = *(const unsigned*)(xf + (size_t)s * NF + 2 * lane);
        }
        #pragma unroll
        for (int q = 0; q < 8; ++q) {
            float g = (q < rem) ? 1.0f : 0.0f;
            float wa = bf2f(wv[q] & 0xffffu), wb = bf2f(wv[q] >> 16);
            float xa = bf2f(xv[q] & 0xffffu), xb = bf2f(xv[q] >> 16);
            a0 = fmaf(xa * g, wa, a0);
            a1 = fmaf(xb * g, wb, a1);
        }
    }
    unsigned pack = (unsigned)(unsigned short)f2bf(a0)
                  | ((unsigned)(unsigned short)f2bf(a1) << 16);
    *(unsigned*)(agg + (size_t)node * NF + 2 * lane) = pack;
}

// h += (ssp(agg@lin2W+b2) @ linW + b3); optionally xf_next = bf16(h_new @ lin1W_next)
// 512 threads / 8 waves: 32 cols per wave.
__global__ __launch_bounds__(512) void update_k(
        const short* __restrict__ aggb, const short* __restrict__ W2T,
        const float* __restrict__ b2, const short* __restrict__ W3T,
        const float* __restrict__ b3, float* __restrict__ h,
        const short* __restrict__ lin1Tn, short* __restrict__ xf_out, int N)
{
    __shared__ short tmp[32 * HID];      // 16 KB bf16, XOR-swizzled rows
    __shared__ float ftmp[32][HID + 4];  // 33 KB fp32, padded
    char* tb = (char*)tmp;
    const int wv = threadIdx.x >> 6, lane = threadIdx.x & 63;
    const int lrow = lane & 15, lgrp = lane >> 4;
    const int r0 = blockIdx.x * 32;

    f32x4 zero = {0.0f, 0.0f, 0.0f, 0.0f};
    f32x4 c1[2][2] = {{zero, zero}, {zero, zero}};

    // matmul1: [32 x 128] @ [128 x 256]
    for (int s = 0; s < 4; ++s) {
        bf16x8 a[2], b[2];
        #pragma unroll
        for (int m = 0; m < 2; ++m) {
            int row = r0 + m * 16 + lrow;
            if (row >= N) row = N - 1;
            a[m] = *(const bf16x8*)(aggb + (size_t)row * NF + s * 32 + lgrp * 8);
        }
        #pragma unroll
        for (int n = 0; n < 2; ++n) {
            int col = wv * 32 + n * 16 + lrow;
            b[n] = *(const bf16x8*)(W2T + (size_t)col * NF + s * 32 + lgrp * 8);
        }
        #pragma unroll
        for (int m = 0; m < 2; ++m)
            #pragma unroll
            for (int n = 0; n < 2; ++n)
                c1[m][n] = __builtin_amdgcn_mfma_f32_16x16x32_bf16(a[m], b[n], c1[m][n], 0, 0, 0);
    }
    #pragma unroll
    for (int m = 0; m < 2; ++m)
        #pragma unroll
        for (int n = 0; n < 2; ++n) {
            int col = wv * 32 + n * 16 + lrow;
            float bb = b2[col];
            #pragma unroll
            for (int j = 0; j < 4; ++j) {
                int row = m * 16 + lgrp * 4 + j;
                int byte = (row * HID + col) * 2;
                byte ^= (row & 7) << 4;
                *(short*)(tb + byte) = f2bf(ssp(c1[m][n][j] + bb));
            }
        }
    __syncthreads();

    f32x4 c2[2][2] = {{zero, zero}, {zero, zero}};
    // matmul2: [32 x 256] @ [256 x 256]
    for (int s = 0; s < 8; ++s) {
        bf16x8 a[2], b[2];
        #pragma unroll
        for (int m = 0; m < 2; ++m) {
            int row = m * 16 + lrow;
            int byte = (row * HID + s * 32 + lgrp * 8) * 2;
            byte ^= (row & 7) << 4;
            a[m] = *(const bf16x8*)(tb + byte);
        }
        #pragma unroll
        for (int n = 0; n < 2; ++n) {
            int col = wv * 32 + n * 16 + lrow;
            b[n] = *(const bf16x8*)(W3T + (size_t)col * HID + s * 32 + lgrp * 8);
        }
        #pragma unroll
        for (int m = 0; m < 2; ++m)
            #pragma unroll
            for (int n = 0; n < 2; ++n)
                c2[m][n] = __builtin_amdgcn_mfma_f32_16x16x32_bf16(a[m], b[n], c2[m][n], 0, 0, 0);
    }

    #pragma unroll
    for (int m = 0; m < 2; ++m)
        #pragma unroll
        for (int n = 0; n < 2; ++n) {
            int col = wv * 32 + n * 16 + lrow;
            float bb = b3[col];
            #pragma unroll
            for (int j = 0; j < 4; ++j)
                ftmp[m * 16 + lgrp * 4 + j][col] = c2[m][n][j] + bb;
        }
    __syncthreads();   // ftmp ready AND matmul2's tmp reads complete

    // coalesced h RMW + bf16(h_new) into swizzled tmp
    {
        const int r  = threadIdx.x >> 4;         // 0..31
        const int c0 = (threadIdx.x & 15) * 4;   // 0..60
        const int row = r0 + r;
        const bool valid = row < N;
        float* hp = h + (size_t)row * HID;
        #pragma unroll
        for (int k = 0; k < 4; ++k) {
            int col = c0 + k * 64;
            float4 hv = valid ? *(const float4*)(hp + col)
                              : make_float4(0.f, 0.f, 0.f, 0.f);
            float4 f = *(const float4*)&ftmp[r][col];
            hv.x += f.x; hv.y += f.y; hv.z += f.z; hv.w += f.w;
            if (valid) *(float4*)(hp + col) = hv;
            short4 s4;
            s4.x = f2bf(hv.x); s4.y = f2bf(hv.y); s4.z = f2bf(hv.z); s4.w = f2bf(hv.w);
            int byte = (r * HID + col) * 2;
            byte ^= (r & 7) << 4;
            *(short4*)(tb + byte) = s4;
        }
    }
    if (xf_out == nullptr) return;
    __syncthreads();

    // stage 3: xf_next = h_new @ lin1W_next   [32 x 256] @ [256 x 128]
    f32x4 c3[2] = {zero, zero};
    for (int s = 0; s < 8; ++s) {
        bf16x8 a[2], b;
        #pragma unroll
        for (int m = 0; m < 2; ++m) {
            int row = m * 16 + lrow;
            int byte = (row * HID + s * 32 + lgrp * 8) * 2;
            byte ^= (row & 7) << 4;
            a[m] = *(const bf16x8*)(tb + byte);
        }
        {
            int col = wv * 16 + lrow;
            b = *(const bf16x8*)(lin1Tn + (size_t)col * HID + s * 32 + lgrp * 8);
        }
        #pragma unroll
        for (int m = 0; m < 2; ++m)
            c3[m] = __builtin_amdgcn_mfma_f32_16x16x32_bf16(a[m], b, c3[m], 0, 0, 0);
    }
    #pragma unroll
    for (int m = 0; m < 2; ++m) {
        int col = wv * 16 + lrow;
        #pragma unroll
        for (int j = 0; j < 4; ++j) {
            int row = r0 + m * 16 + lgrp * 4 + j;
            if (row < N) xf_out[(size_t)row * NF + col] = f2bf(c3[m][j]);
        }
    }
}

// Stage 1: partial max. grid (NGRAPH, PSLICE); each block serial-maxes a fixed
// slice of its graph's rows (deterministic: fixed boundaries, serial order).
__global__ __launch_bounds__(256) void pool_partial(
        const float* __restrict__ h, const int* __restrict__ seg,
        float* __restrict__ pooledP, int N)
{
    const int g = blockIdx.x, sl = blockIdx.y, c = threadIdx.x;
    int lo, hi;
    {
        int a = 0, b = N;
        while (a < b) { int m = (a + b) >> 1; if (seg[m] < g) a = m + 1; else b = m; }
        lo = a;
        b = N;
        while (a < b) { int m = (a + b) >> 1; if (seg[m] < g + 1) a = m + 1; else b = m; }
        hi = a;
    }
    const int len = hi - lo;
    const int chunk = (len + PSLICE - 1) / PSLICE;
    const int s0 = lo + sl * chunk;
    const int s1 = min(s0 + chunk, hi);

    float m0 = -INFINITY, m1 = -INFINITY, m2 = -INFINITY, m3 = -INFINITY;
    int r = s0;
    for (; r + 4 <= s1; r += 4) {
        m0 = fmaxf(m0, h[(size_t)(r    ) * HID + c]);
        m1 = fmaxf(m1, h[(size_t)(r + 1) * HID + c]);
        m2 = fmaxf(m2, h[(size_t)(r + 2) * HID + c]);
        m3 = fmaxf(m3, h[(size_t)(r + 3) * HID + c]);
    }
    for (; r < s1; ++r) m0 = fmaxf(m0, h[(size_t)r * HID + c]);
    pooledP[((size_t)g * PSLICE + sl) * HID + c] = fmaxf(fmaxf(m0, m1), fmaxf(m2, m3));
}

// Stage 2: reduce partials (fixed order) + 2-layer MLP, k-split x4.
__global__ __launch_bounds__(1024) void final_mlp(
        const float* __restrict__ pooledP,
        const float* __restrict__ fW1, const float* __restrict__ fb1,
        const float* __restrict__ fW2, const float* __restrict__ fb2,
        float* __restrict__ out)
{
    __shared__ float p[HID];
    __shared__ float part[4][HID];
    __shared__ float p2[HID];
    const int g = blockIdx.x;
    const int c = threadIdx.x & 255;
    const int kq = threadIdx.x >> 8;
    if (threadIdx.x < HID) {
        float m = -INFINITY;
        #pragma unroll
        for (int s = 0; s < PSLICE; ++s)
            m = fmaxf(m, pooledP[((size_t)g * PSLICE + s) * HID + threadIdx.x]);
        p[threadIdx.x] = m;
    }
    __syncthreads();
    float a = 0.0f;
    #pragma unroll 8
    for (int k = kq * 64; k < kq * 64 + 64; ++k)
        a = fmaf(p[k], fW1[(size_t)k * HID + c], a);
    part[kq][c] = a;
    __syncthreads();
    if (kq == 0) {
        float s = part[0][c] + part[1][c] + part[2][c] + part[3][c] + fb1[c];
        p2[c] = fmaxf(s, 0.0f);
    }
    __syncthreads();
    float o = 0.0f;
    #pragma unroll 8
    for (int k = kq * 64; k < kq * 64 + 64; ++k)
        o = fmaf(p2[k], fW2[(size_t)k * HID + c], o);
    part[kq][c] = o;
    __syncthreads();
    if (kq == 0)
        out[(size_t)g * HID + c] = part[0][c] + part[1][c] + part[2][c] + part[3][c] + fb2[c];
}

extern "C" void kernel_launch(void* const* d_in, const int* in_sizes, int n_in,
                              void* d_out, int out_size, void* d_ws, size_t ws_size,
                              hipStream_t stream)
{
    const int*   atom_types = (const int*)  d_in[0];
    const int*   edge_index = (const int*)  d_in[1];
    const float* edge_len   = (const float*)d_in[2];
    const int*   batch_seg  = (const int*)  d_in[3];
    const float* atom_emb   = (const float*)d_in[4];
    const float* W1s    = (const float*)d_in[5];
    const float* b1s    = (const float*)d_in[6];
    const float* W2s    = (const float*)d_in[7];
    const float* b2s    = (const float*)d_in[8];
    const float* lin1Ws = (const float*)d_in[9];
    const float* lin2Ws = (const float*)d_in[10];
    const float* lin2bs = (const float*)d_in[11];
    const float* linWs  = (const float*)d_in[12];
    const float* linbs  = (const float*)d_in[13];
    const float* fW1    = (const float*)d_in[14];
    const float* fb1    = (const float*)d_in[15];
    const float* fW2    = (const float*)d_in[16];
    const float* fb2    = (const float*)d_in[17];

    const int N = in_sizes[0];
    const int E = in_sizes[1] / 2;
    const int* src = edge_index;
    const int* dst = edge_index + E;

    char* ws = (char*)d_ws;
    float* h     = (float*)ws;  ws += (size_t)N * HID * sizeof(float);
    short* xf    = (short*)ws;  ws += (size_t)N * NF * sizeof(short);
    short* aggb  = (short*)ws;  ws += (size_t)N * NF * sizeof(short);
    short* Wtab  = (short*)ws;  ws += (size_t)NBLK * (T_TAB + 1) * NF * sizeof(short);
    short* lin1T = (short*)ws;  ws += (size_t)NBLK * NF * HID * sizeof(short);
    short* W2T   = (short*)ws;  ws += (size_t)NBLK * HID * NF * sizeof(short);
    short* W3T   = (short*)ws;  ws += (size_t)NBLK * HID * HID * sizeof(short);
    short* W1Tb  = (short*)ws;  ws += (size_t)NBLK * NF * NF * sizeof(short);
    short* W2Tb  = (short*)ws;  ws += (size_t)NBLK * NF * NF * sizeof(short);
    float* pooledP = (float*)ws; ws += (size_t)NGRAPH * PSLICE * HID * sizeof(float);
    unsigned long long* csr_pk = (unsigned long long*)ws; ws += (size_t)E * sizeof(unsigned long long);
    int* hist    = (int*)ws;  ws += (size_t)N * sizeof(int);
    int* off     = (int*)ws;  ws += (size_t)(N + 1) * sizeof(int);
    int* cursor  = (int*)ws;

    hipMemsetAsync(hist, 0, (size_t)N * sizeof(int), stream);
    hipMemsetAsync(cursor, 0, (size_t)N * sizeof(int), stream);
    hist_k<<<(E + 255) / 256, 256, 0, stream>>>(dst, hist, E);
    scan_k<<<1, 1024, 0, stream>>>(hist, off, N);
    scatter_k<<<(E + 255) / 256, 256, 0, stream>>>(src, dst, edge_len, off,
                                                   cursor, csr_pk, E);
    sort_k<<<(N * 64 + 255) / 256, 256, 0, stream>>>(off, csr_pk, N);

    prep_weights<<<dim3((HID * HID + 255) / 256, NBLK, 5), 256, 0, stream>>>(
        W1s, W1Tb, W2s, W2Tb, lin1Ws, lin1T, lin2Ws, W2T, linWs, W3T);

    build_table_mfma<<<dim3(T_TAB / 32, NBLK), 256, 0, stream>>>(W1Tb, b1s, W2Tb, b2s, Wtab);
    zero_sink<<<NBLK, 128, 0, stream>>>(Wtab);
    embed_k<<<(N * HID + 255) / 256, 256, 0, stream>>>(atom_emb, atom_types, h, N);
    lin1_k<<<(N + 63) / 64, 256, 0, stream>>>(h, lin1T, xf, N);

    for (int i = 0; i < NBLK; ++i) {
        agg_k<<<(N * 64 + 255) / 256, 256, 0, stream>>>(
            xf, Wtab + (size_t)i * (T_TAB + 1) * NF, off, csr_pk, aggb, N);
        update_k<<<(N + 31) / 32, 512, 0, stream>>>(
            aggb, W2T + (size_t)i * HID * NF, lin2bs + (size_t)i * HID,
            W3T + (size_t)i * HID * HID, linbs + (size_t)i * HID, h,
            lin1T + (size_t)(i + 1) * NF * HID,
            (i < NBLK - 1) ? xf : nullptr, N);
    }

    pool_partial<<<dim3(NGRAPH, PSLICE), 256, 0, stream>>>(h, batch_seg, pooledP, N);
    final_mlp<<<NGRAPH, 1024, 0, stream>>>(pooledP, fW1, fb1, fW2, fb2, (float*)d_out);
}

// Round 17
// 551.601 us; speedup vs baseline: 1.0086x; 1.0086x over previous
//
#include <hip/hip_runtime.h>
#include <math.h>

#define HID 256
#define NF 128
#define NGAUSS 100
#define NBLK 6
#define NGRAPH 64
#define CUTOFF_F 10.0f
#define T_TAB 8192
#define PSLICE 8

typedef __attribute__((ext_vector_type(8))) short bf16x8;
typedef __attribute__((ext_vector_type(4))) float f32x4;

__device__ __forceinline__ float ssp(float x) {
    return fmaxf(x, 0.0f) + log1pf(expf(-fabsf(x))) - 0.69314718056f;
}
__device__ __forceinline__ short f2bf(float f) {
    unsigned u = __float_as_uint(f);
    u = u + 0x7fffu + ((u >> 16) & 1u);
    return (short)(u >> 16);
}
__device__ __forceinline__ float bf2f(unsigned s) {
    return __uint_as_float(s << 16);
}

// All 5 weight transposes in one launch: grid.z selects the segment.
__global__ __launch_bounds__(256) void prep_weights(
        const float* __restrict__ W1s,   short* __restrict__ W1Tb,
        const float* __restrict__ W2s,   short* __restrict__ W2Tb,
        const float* __restrict__ lin1Ws, short* __restrict__ lin1T,
        const float* __restrict__ lin2Ws, short* __restrict__ W2T,
        const float* __restrict__ linWs,  short* __restrict__ W3T)
{
    const float* in; short* out; int Ks, Kp, C;
    switch (blockIdx.z) {
        case 0: in = W1s;    out = W1Tb;  Ks = NGAUSS; Kp = NF;  C = NF;  break;
        case 1: in = W2s;    out = W2Tb;  Ks = NF;     Kp = NF;  C = NF;  break;
        case 2: in = lin1Ws; out = lin1T; Ks = HID;    Kp = HID; C = NF;  break;
        case 3: in = lin2Ws; out = W2T;   Ks = NF;     Kp = NF;  C = HID; break;
        default: in = linWs; out = W3T;   Ks = HID;    Kp = HID; C = HID; break;
    }
    int i = blockIdx.y;
    int idx = blockIdx.x * 256 + threadIdx.x;
    if (idx >= Kp * C) return;
    int k = idx / C, c = idx % C;
    out[((size_t)i * C + c) * Kp + k] =
        (k < Ks) ? f2bf(in[((size_t)i * Ks + k) * C + c]) : (short)0;
}

// Wtab[i][t][c] = (ssp(gauss(d_t) @ W1_i + b1_i) @ W2_i + b2_i)[c] via MFMA.
// Layout: [i][(T_TAB+1)][NF]; row T_TAB = zero sink (gated edges).
__global__ __launch_bounds__(256) void build_table_mfma(
        const short* __restrict__ W1T, const float* __restrict__ b1s,
        const short* __restrict__ W2T, const float* __restrict__ b2s,
        short* __restrict__ Wtab)
{
    __shared__ short Gs[32 * NF];
    __shared__ short Hs[32 * NF];
    char* gb = (char*)Gs;
    char* hb = (char*)Hs;
    const int i = blockIdx.y;
    const int r0 = blockIdx.x * 32;
    const int wv = threadIdx.x >> 6, lane = threadIdx.x & 63;
    const int lrow = lane & 15, lgrp = lane >> 4;

    const float delta = CUTOFF_F / 99.0f;
    const float coeff = -0.5f / (delta * delta);
    for (int idx = threadIdx.x; idx < 32 * NF; idx += 256) {
        int row = idx >> 7, k = idx & 127;
        float d = (float)(r0 + row) * (CUTOFF_F / (float)(T_TAB - 1));
        float x = d - (float)k * delta;
        float v = (k < NGAUSS) ? expf(coeff * x * x) : 0.0f;
        int byte = idx * 2;
        byte ^= (row & 7) << 4;
        *(short*)(gb + byte) = f2bf(v);
    }
    __syncthreads();

    f32x4 zero = {0.0f, 0.0f, 0.0f, 0.0f};
    f32x4 c1[2][2] = {{zero, zero}, {zero, zero}};
    for (int s = 0; s < 4; ++s) {
        bf16x8 a[2], b[2];
        #pragma unroll
        for (int m = 0; m < 2; ++m) {
            int row = m * 16 + lrow;
            int byte = (row * NF + s * 32 + lgrp * 8) * 2;
            byte ^= (row & 7) << 4;
            a[m] = *(const bf16x8*)(gb + byte);
        }
        #pragma unroll
        for (int n = 0; n < 2; ++n) {
            int col = wv * 32 + n * 16 + lrow;
            b[n] = *(const bf16x8*)(W1T + ((size_t)i * NF + col) * NF + s * 32 + lgrp * 8);
        }
        #pragma unroll
        for (int m = 0; m < 2; ++m)
            #pragma unroll
            for (int n = 0; n < 2; ++n)
                c1[m][n] = __builtin_amdgcn_mfma_f32_16x16x32_bf16(a[m], b[n], c1[m][n], 0, 0, 0);
    }
    #pragma unroll
    for (int m = 0; m < 2; ++m)
        #pragma unroll
        for (int n = 0; n < 2; ++n) {
            int col = wv * 32 + n * 16 + lrow;
            float bb = b1s[i * NF + col];
            #pragma unroll
            for (int j = 0; j < 4; ++j) {
                int row = m * 16 + lgrp * 4 + j;
                int byte = (row * NF + col) * 2;
                byte ^= (row & 7) << 4;
                *(short*)(hb + byte) = f2bf(ssp(c1[m][n][j] + bb));
            }
        }
    __syncthreads();

    f32x4 c2[2][2] = {{zero, zero}, {zero, zero}};
    for (int s = 0; s < 4; ++s) {
        bf16x8 a[2], b[2];
        #pragma unroll
        for (int m = 0; m < 2; ++m) {
            int row = m * 16 + lrow;
            int byte = (row * NF + s * 32 + lgrp * 8) * 2;
            byte ^= (row & 7) << 4;
            a[m] = *(const bf16x8*)(hb + byte);
        }
        #pragma unroll
        for (int n = 0; n < 2; ++n) {
            int col = wv * 32 + n * 16 + lrow;
            b[n] = *(const bf16x8*)(W2T + ((size_t)i * NF + col) * NF + s * 32 + lgrp * 8);
        }
        #pragma unroll
        for (int m = 0; m < 2; ++m)
            #pragma unroll
            for (int n = 0; n < 2; ++n)
                c2[m][n] = __builtin_amdgcn_mfma_f32_16x16x32_bf16(a[m], b[n], c2[m][n], 0, 0, 0);
    }
    #pragma unroll
    for (int m = 0; m < 2; ++m)
        #pragma unroll
        for (int n = 0; n < 2; ++n) {
            int col = wv * 32 + n * 16 + lrow;
            float bb = b2s[i * NF + col];
            #pragma unroll
            for (int j = 0; j < 4; ++j) {
                int t = r0 + m * 16 + lgrp * 4 + j;
                Wtab[((size_t)i * (T_TAB + 1) + t) * NF + col] = f2bf(c2[m][n][j] + bb);
            }
        }
}

// zero the sink row (index T_TAB) of each interaction block's table
__global__ __launch_bounds__(128) void zero_sink(short* __restrict__ Wtab)
{
    Wtab[((size_t)blockIdx.x * (T_TAB + 1) + T_TAB) * NF + threadIdx.x] = 0;
}

__global__ __launch_bounds__(256) void embed_k(
        const float* __restrict__ emb, const int* __restrict__ types,
        float* __restrict__ h, int N)
{
    int gid = blockIdx.x * 256 + threadIdx.x;
    if (gid >= N * HID) return;
    int n = gid >> 8, c = gid & (HID - 1);
    h[gid] = emb[(size_t)types[n] * HID + c];
}

// ---------------- CSR build ----------------
__global__ __launch_bounds__(256) void hist_k(
        const int* __restrict__ dst, int* __restrict__ hist, int E)
{
    int e = blockIdx.x * 256 + threadIdx.x;
    if (e < E) atomicAdd(&hist[dst[e]], 1);
}

__global__ __launch_bounds__(1024) void scan_k(
        const int* __restrict__ in, int* __restrict__ out, int n)
{
    __shared__ int wsum[16];
    __shared__ int carry_s;
    const int tid = threadIdx.x, lane = tid & 63, w = tid >> 6;
    if (tid == 0) carry_s = 0;
    __syncthreads();
    for (int base = 0; base < n; base += 1024) {
        int i = base + tid;
        int v = (i < n) ? in[i] : 0;
        int s = v;
        #pragma unroll
        for (int d = 1; d < 64; d <<= 1) {
            int t = __shfl_up(s, d);
            if (lane >= d) s += t;
        }
        if (lane == 63) wsum[w] = s;
        __syncthreads();
        if (w == 0 && lane < 16) {
            int ws = wsum[lane];
            #pragma unroll
            for (int d = 1; d < 16; d <<= 1) {
                int t = __shfl_up(ws, d);
                if (lane >= d) ws += t;
            }
            wsum[lane] = ws;
        }
        __syncthreads();
        int carry = carry_s;
        if (i < n) out[i] = carry + (w ? wsum[w - 1] : 0) + s - v;
        __syncthreads();
        if (tid == 1023) carry_s = carry + wsum[15];
        __syncthreads();
    }
    if (threadIdx.x == 0) out[n] = carry_s;
}

// packed (i0<<32 | src); i0 = nearest table index (precomputed),
// gated edges -> i0 = T_TAB (zero sink row).
__global__ __launch_bounds__(256) void scatter_k(
        const int* __restrict__ src, const int* __restrict__ dst,
        const float* __restrict__ elen, const int* __restrict__ off,
        int* __restrict__ cursor, unsigned long long* __restrict__ csr_pk, int E)
{
    int e = blockIdx.x * 256 + threadIdx.x;
    if (e >= E) return;
    int t = dst[e];
    int pos = off[t] + atomicAdd(&cursor[t], 1);
    float d = elen[e];
    float u = d * ((float)(T_TAB - 1) / CUTOFF_F);
    int i0 = (int)(fminf(fmaxf(u, 0.0f), (float)(T_TAB - 1)) + 0.5f);
    if (i0 > T_TAB - 1) i0 = T_TAB - 1;
    if (d > CUTOFF_F) i0 = T_TAB;   // zero sink
    csr_pk[pos] = ((unsigned long long)(unsigned)i0 << 32) | (unsigned)src[e];
}

// one-time canonical sort of each CSR row: scatter order varies per call,
// sorted content does not -> downstream accumulation is bit-deterministic.
__global__ __launch_bounds__(256) void sort_k(
        const int* __restrict__ off, unsigned long long* __restrict__ csr_pk, int N)
{
    const int node = (blockIdx.x * 256 + threadIdx.x) >> 6;
    const int lane = threadIdx.x & 63;
    if (node >= N) return;
    const int beg = off[node], end = off[node + 1];
    const int deg = end - beg;
    if (deg <= 1) return;
    if (deg <= 128) {
        const unsigned long long PAD = ~0ull;
        unsigned long long v0 = (lane < deg) ? csr_pk[beg + lane] : PAD;
        unsigned long long v1 = (64 + lane < deg) ? csr_pk[beg + 64 + lane] : PAD;
        if (deg > 64) {
            for (int size = 2; size <= 128; size <<= 1)
                for (int stride = size >> 1; stride > 0; stride >>= 1) {
                    if (stride == 64) {
                        unsigned long long lo = v0 < v1 ? v0 : v1;
                        unsigned long long hi = v0 < v1 ? v1 : v0;
                        v0 = lo; v1 = hi;
                    } else {
                        unsigned long long p0 = __shfl_xor(v0, stride);
                        unsigned long long p1 = __shfl_xor(v1, stride);
                        bool up = (lane & stride) != 0;
                        bool d0 = ((lane & size) == 0);
                        bool d1 = (((lane + 64) & size) == 0);
                        v0 = (up ^ d0) ? (v0 < p0 ? v0 : p0) : (v0 > p0 ? v0 : p0);
                        v1 = (up ^ d1) ? (v1 < p1 ? v1 : p1) : (v1 > p1 ? v1 : p1);
                    }
                }
            if (lane < deg) csr_pk[beg + lane] = v0;
            if (64 + lane < deg) csr_pk[beg + 64 + lane] = v1;
        } else {
            for (int size = 2; size <= 64; size <<= 1)
                for (int stride = size >> 1; stride > 0; stride >>= 1) {
                    unsigned long long p0 = __shfl_xor(v0, stride);
                    bool up = (lane & stride) != 0;
                    bool d0 = ((lane & size) == 0);
                    v0 = (up ^ d0) ? (v0 < p0 ? v0 : p0) : (v0 > p0 ? v0 : p0);
                }
            if (lane < deg) csr_pk[beg + lane] = v0;
        }
    } else if (lane == 0) {
        for (int a = beg + 1; a < end; ++a) {
            unsigned long long key = csr_pk[a];
            int b = a - 1;
            while (b >= beg && csr_pk[b] > key) { csr_pk[b + 1] = csr_pk[b]; --b; }
            csr_pk[b + 1] = key;
        }
    }
}

// ---------------- per-block kernels ----------------

// xf = bf16(h @ lin1W)  (block 0 only; later blocks fused into update_k)
__global__ __launch_bounds__(256) void lin1_k(
        const float* __restrict__ h, const short* __restrict__ lin1T,
        short* __restrict__ xf, int N)
{
    const int wv = threadIdx.x >> 6, lane = threadIdx.x & 63;
    const int lrow = lane & 15, lgrp = lane >> 4;
    const int wrow = wv >> 1, wcol = wv & 1;
    const int r0 = blockIdx.x * 64 + wrow * 32;

    f32x4 zero = {0.0f, 0.0f, 0.0f, 0.0f};
    f32x4 c[2][4] = {{zero, zero, zero, zero}, {zero, zero, zero, zero}};

    for (int s = 0; s < 8; ++s) {
        bf16x8 a[2], b[4];
        #pragma unroll
        for (int m = 0; m < 2; ++m) {
            int row = r0 + m * 16 + lrow;
            if (row >= N) row = N - 1;
            const float* hp = h + (size_t)row * HID + s * 32 + lgrp * 8;
            float4 p0 = *(const float4*)hp;
            float4 p1 = *(const float4*)(hp + 4);
            bf16x8 t;
            t[0] = f2bf(p0.x); t[1] = f2bf(p0.y); t[2] = f2bf(p0.z); t[3] = f2bf(p0.w);
            t[4] = f2bf(p1.x); t[5] = f2bf(p1.y); t[6] = f2bf(p1.z); t[7] = f2bf(p1.w);
            a[m] = t;
        }
        #pragma unroll
        for (int n = 0; n < 4; ++n) {
            int col = wcol * 64 + n * 16 + lrow;
            b[n] = *(const bf16x8*)(lin1T + (size_t)col * HID + s * 32 + lgrp * 8);
        }
        #pragma unroll
        for (int m = 0; m < 2; ++m)
            #pragma unroll
            for (int n = 0; n < 4; ++n)
                c[m][n] = __builtin_amdgcn_mfma_f32_16x16x32_bf16(a[m], b[n], c[m][n], 0, 0, 0);
    }
    #pragma unroll
    for (int m = 0; m < 2; ++m)
        #pragma unroll
        for (int n = 0; n < 4; ++n) {
            int col = wcol * 64 + n * 16 + lrow;
            #pragma unroll
            for (int j = 0; j < 4; ++j) {
                int row = r0 + m * 16 + lgrp * 4 + j;
                if (row < N) xf[(size_t)row * NF + col] = f2bf(c[m][n][j]);
            }
        }
}

// one wave per dst node; sorted keys carry precomputed nearest table index ->
// per edge: 2 loads + 4 unpacks + 2 FMA. 8-wide gather groups.
__global__ __launch_bounds__(256) void agg_k(
        const short* __restrict__ xf, const short* __restrict__ wt,
        const int* __restrict__ off, const unsigned long long* __restrict__ csr_pk,
        short* __restrict__ agg, int N)
{
    const int node = (blockIdx.x * 256 + threadIdx.x) >> 6;
    const int lane = threadIdx.x & 63;
    if (node >= N) return;
    const int beg = __builtin_amdgcn_readfirstlane(off[node]);
    const int end = __builtin_amdgcn_readfirstlane(off[node + 1]);
    float a0 = 0.0f, a1 = 0.0f;

    int k = beg;
    for (; k + 8 <= end; k += 8) {
        unsigned long long pk[8];
        #pragma unroll
        for (int q = 0; q < 8; ++q) pk[q] = csr_pk[k + q];
        unsigned wv[8], xv[8];
        #pragma unroll
        for (int q = 0; q < 8; ++q) {
            int i0 = (int)(pk[q] >> 32);
            int s  = (int)(unsigned)pk[q];
            wv[q] = *(const unsigned*)(wt + (size_t)i0 * NF + 2 * lane);
            xv[q] = *(const unsigned*)(xf + (size_t)s * NF + 2 * lane);
        }
        #pragma unroll
        for (int q = 0; q < 8; ++q) {
            float wa = bf2f(wv[q] & 0xffffu), wb = bf2f(wv[q] >> 16);
            float xa = bf2f(xv[q] & 0xffffu), xb = bf2f(xv[q] >> 16);
            a0 = fmaf(xa, wa, a0);
            a1 = fmaf(xb, wb, a1);
        }
    }
    if (k < end) {
        const int rem = end - k;
        unsigned long long pk[8];
        #pragma unroll
        for (int q = 0; q < 8; ++q) {
            int kk = k + q < end ? k + q : end - 1;
            pk[q] = csr_pk[kk];
        }
        unsigned wv[8], xv[8];
        #pragma unroll
        for (int q = 0; q < 8; ++q) {
            int i0 = (int)(pk[q] >> 32);
            int s  = (int)(unsigned)pk[q];
            wv[q] = *(const unsigned*)(wt + (size_t)i0 * NF + 2 * lane);
            xv[q] = *(const unsigned*)(xf + (size_t)s * NF + 2 * lane);
        }
        #pragma unroll
        for (int q = 0; q < 8; ++q) {
            float g = (q < rem) ? 1.0f : 0.0f;
            float wa = bf2f(wv[q] & 0xffffu), wb = bf2f(wv[q] >> 16);
            float xa = bf2f(xv[q] & 0xffffu), xb = bf2f(xv[q] >> 16);
            a0 = fmaf(xa * g, wa, a0);
            a1 = fmaf(xb * g, wb, a1);
        }
    }
    unsigned pack = (unsigned)(unsigned short)f2bf(a0)
                  | ((unsigned)(unsigned short)f2bf(a1) << 16);
    *(unsigned*)(agg + (size_t)node * NF + 2 * lane) = pack;
}

// h += (ssp(agg@lin2W+b2) @ linW + b3); optionally xf_next = bf16(h_new @ lin1W_next)
// 512 threads / 8 waves: 32 cols per wave.
__global__ __launch_bounds__(512) void update_k(
        const short* __restrict__ aggb, const short* __restrict__ W2T,
        const float* __restrict__ b2, const short* __restrict__ W3T,
        const float* __restrict__ b3, float* __restrict__ h,
        const short* __restrict__ lin1Tn, short* __restrict__ xf_out, int N)
{
    __shared__ short tmp[32 * HID];      // 16 KB bf16, XOR-swizzled rows
    __shared__ float ftmp[32][HID + 4];  // 33 KB fp32, padded
    char* tb = (char*)tmp;
    const int wv = threadIdx.x >> 6, lane = threadIdx.x & 63;
    const int lrow = lane & 15, lgrp = lane >> 4;
    const int r0 = blockIdx.x * 32;

    f32x4 zero = {0.0f, 0.0f, 0.0f, 0.0f};
    f32x4 c1[2][2] = {{zero, zero}, {zero, zero}};

    // matmul1: [32 x 128] @ [128 x 256]
    for (int s = 0; s < 4; ++s) {
        bf16x8 a[2], b[2];
        #pragma unroll
        for (int m = 0; m < 2; ++m) {
            int row = r0 + m * 16 + lrow;
            if (row >= N) row = N - 1;
            a[m] = *(const bf16x8*)(aggb + (size_t)row * NF + s * 32 + lgrp * 8);
        }
        #pragma unroll
        for (int n = 0; n < 2; ++n) {
            int col = wv * 32 + n * 16 + lrow;
            b[n] = *(const bf16x8*)(W2T + (size_t)col * NF + s * 32 + lgrp * 8);
        }
        #pragma unroll
        for (int m = 0; m < 2; ++m)
            #pragma unroll
            for (int n = 0; n < 2; ++n)
                c1[m][n] = __builtin_amdgcn_mfma_f32_16x16x32_bf16(a[m], b[n], c1[m][n], 0, 0, 0);
    }
    #pragma unroll
    for (int m = 0; m < 2; ++m)
        #pragma unroll
        for (int n = 0; n < 2; ++n) {
            int col = wv * 32 + n * 16 + lrow;
            float bb = b2[col];
            #pragma unroll
            for (int j = 0; j < 4; ++j) {
                int row = m * 16 + lgrp * 4 + j;
                int byte = (row * HID + col) * 2;
                byte ^= (row & 7) << 4;
                *(short*)(tb + byte) = f2bf(ssp(c1[m][n][j] + bb));
            }
        }
    __syncthreads();

    f32x4 c2[2][2] = {{zero, zero}, {zero, zero}};
    // matmul2: [32 x 256] @ [256 x 256]
    for (int s = 0; s < 8; ++s) {
        bf16x8 a[2], b[2];
        #pragma unroll
        for (int m = 0; m < 2; ++m) {
            int row = m * 16 + lrow;
            int byte = (row * HID + s * 32 + lgrp * 8) * 2;
            byte ^= (row & 7) << 4;
            a[m] = *(const bf16x8*)(tb + byte);
        }
        #pragma unroll
        for (int n = 0; n < 2; ++n) {
            int col = wv * 32 + n * 16 + lrow;
            b[n] = *(const bf16x8*)(W3T + (size_t)col * HID + s * 32 + lgrp * 8);
        }
        #pragma unroll
        for (int m = 0; m < 2; ++m)
            #pragma unroll
            for (int n = 0; n < 2; ++n)
                c2[m][n] = __builtin_amdgcn_mfma_f32_16x16x32_bf16(a[m], b[n], c2[m][n], 0, 0, 0);
    }

    #pragma unroll
    for (int m = 0; m < 2; ++m)
        #pragma unroll
        for (int n = 0; n < 2; ++n) {
            int col = wv * 32 + n * 16 + lrow;
            float bb = b3[col];
            #pragma unroll
            for (int j = 0; j < 4; ++j)
                ftmp[m * 16 + lgrp * 4 + j][col] = c2[m][n][j] + bb;
        }
    __syncthreads();   // ftmp ready AND matmul2's tmp reads complete

    // coalesced h RMW + bf16(h_new) into swizzled tmp
    {
        const int r  = threadIdx.x >> 4;         // 0..31
        const int c0 = (threadIdx.x & 15) * 4;   // 0..60
        const int row = r0 + r;
        const bool valid = row < N;
        float* hp = h + (size_t)row * HID;
        #pragma unroll
        for (int k = 0; k < 4; ++k) {
            int col = c0 + k * 64;
            float4 hv = valid ? *(const float4*)(hp + col)
                              : make_float4(0.f, 0.f, 0.f, 0.f);
            float4 f = *(const float4*)&ftmp[r][col];
            hv.x += f.x; hv.y += f.y; hv.z += f.z; hv.w += f.w;
            if (valid) *(float4*)(hp + col) = hv;
            short4 s4;
            s4.x = f2bf(hv.x); s4.y = f2bf(hv.y); s4.z = f2bf(hv.z); s4.w = f2bf(hv.w);
            int byte = (r * HID + col) * 2;
            byte ^= (r & 7) << 4;
            *(short4*)(tb + byte) = s4;
        }
    }
    if (xf_out == nullptr) return;
    __syncthreads();

    // stage 3: xf_next = h_new @ lin1W_next   [32 x 256] @ [256 x 128]
    f32x4 c3[2] = {zero, zero};
    for (int s = 0; s < 8; ++s) {
        bf16x8 a[2], b;
        #pragma unroll
        for (int m = 0; m < 2; ++m) {
            int row = m * 16 + lrow;
            int byte = (row * HID + s * 32 + lgrp * 8) * 2;
            byte ^= (row & 7) << 4;
            a[m] = *(const bf16x8*)(tb + byte);
        }
        {
            int col = wv * 16 + lrow;
            b = *(const bf16x8*)(lin1Tn + (size_t)col * HID + s * 32 + lgrp * 8);
        }
        #pragma unroll
        for (int m = 0; m < 2; ++m)
            c3[m] = __builtin_amdgcn_mfma_f32_16x16x32_bf16(a[m], b, c3[m], 0, 0, 0);
    }
    #pragma unroll
    for (int m = 0; m < 2; ++m) {
        int col = wv * 16 + lrow;
        #pragma unroll
        for (int j = 0; j < 4; ++j) {
            int row = r0 + m * 16 + lgrp * 4 + j;
            if (row < N) xf_out[(size_t)row * NF + col] = f2bf(c3[m][j]);
        }
    }
}

// Stage 1: partial max. grid (NGRAPH, PSLICE); each block serial-maxes a fixed
// slice of its graph's rows (deterministic: fixed boundaries, serial order).
__global__ __launch_bounds__(256) void pool_partial(
        const float* __restrict__ h, const int* __restrict__ seg,
        float* __restrict__ pooledP, int N)
{
    const int g = blockIdx.x, sl = blockIdx.y, c = threadIdx.x;
    int lo, hi;
    {
        int a = 0, b = N;
        while (a < b) { int m = (a + b) >> 1; if (seg[m] < g) a = m + 1; else b = m; }
        lo = a;
        b = N;
        while (a < b) { int m = (a + b) >> 1; if (seg[m] < g + 1) a = m + 1; else b = m; }
        hi = a;
    }
    const int len = hi - lo;
    const int chunk = (len + PSLICE - 1) / PSLICE;
    const int s0 = lo + sl * chunk;
    const int s1 = min(s0 + chunk, hi);

    float m0 = -INFINITY, m1 = -INFINITY, m2 = -INFINITY, m3 = -INFINITY;
    int r = s0;
    for (; r + 4 <= s1; r += 4) {
        m0 = fmaxf(m0, h[(size_t)(r    ) * HID + c]);
        m1 = fmaxf(m1, h[(size_t)(r + 1) * HID + c]);
        m2 = fmaxf(m2, h[(size_t)(r + 2) * HID + c]);
        m3 = fmaxf(m3, h[(size_t)(r + 3) * HID + c]);
    }
    for (; r < s1; ++r) m0 = fmaxf(m0, h[(size_t)r * HID + c]);
    pooledP[((size_t)g * PSLICE + sl) * HID + c] = fmaxf(fmaxf(m0, m1), fmaxf(m2, m3));
}

// Stage 2: reduce partials (fixed order) + 2-layer MLP, k-split x4.
__global__ __launch_bounds__(1024) void final_mlp(
        const float* __restrict__ pooledP,
        const float* __restrict__ fW1, const float* __restrict__ fb1,
        const float* __restrict__ fW2, const float* __restrict__ fb2,
        float* __restrict__ out)
{
    __shared__ float p[HID];
    __shared__ float part[4][HID];
    __shared__ float p2[HID];
    const int g = blockIdx.x;
    const int c = threadIdx.x & 255;
    const int kq = threadIdx.x >> 8;
    if (threadIdx.x < HID) {
        float m = -INFINITY;
        #pragma unroll
        for (int s = 0; s < PSLICE; ++s)
            m = fmaxf(m, pooledP[((size_t)g * PSLICE + s) * HID + threadIdx.x]);
        p[threadIdx.x] = m;
    }
    __syncthreads();
    float a = 0.0f;
    #pragma unroll 8
    for (int k = kq * 64; k < kq * 64 + 64; ++k)
        a = fmaf(p[k], fW1[(size_t)k * HID + c], a);
    part[kq][c] = a;
    __syncthreads();
    if (kq == 0) {
        float s = part[0][c] + part[1][c] + part[2][c] + part[3][c] + fb1[c];
        p2[c] = fmaxf(s, 0.0f);
    }
    __syncthreads();
    float o = 0.0f;
    #pragma unroll 8
    for (int k = kq * 64; k < kq * 64 + 64; ++k)
        o = fmaf(p2[k], fW2[(size_t)k * HID + c], o);
    part[kq][c] = o;
    __syncthreads();
    if (kq == 0)
        out[(size_t)g * HID + c] = part[0][c] + part[1][c] + part[2][c] + part[3][c] + fb2[c];
}

extern "C" void kernel_launch(void* const* d_in, const int* in_sizes, int n_in,
                              void* d_out, int out_size, void* d_ws, size_t ws_size,
                              hipStream_t stream)
{
    const int*   atom_types = (const int*)  d_in[0];
    const int*   edge_index = (const int*)  d_in[1];
    const float* edge_len   = (const float*)d_in[2];
    const int*   batch_seg  = (const int*)  d_in[3];
    const float* atom_emb   = (const float*)d_in[4];
    const float* W1s    = (const float*)d_in[5];
    const float* b1s    = (const float*)d_in[6];
    const float* W2s    = (const float*)d_in[7];
    const float* b2s    = (const float*)d_in[8];
    const float* lin1Ws = (const float*)d_in[9];
    const float* lin2Ws = (const float*)d_in[10];
    const float* lin2bs = (const float*)d_in[11];
    const float* linWs  = (const float*)d_in[12];
    const float* linbs  = (const float*)d_in[13];
    const float* fW1    = (const float*)d_in[14];
    const float* fb1    = (const float*)d_in[15];
    const float* fW2    = (const float*)d_in[16];
    const float* fb2    = (const float*)d_in[17];

    const int N = in_sizes[0];
    const int E = in_sizes[1] / 2;
    const int* src = edge_index;
    const int* dst = edge_index + E;

    char* ws = (char*)d_ws;
    float* h     = (float*)ws;  ws += (size_t)N * HID * sizeof(float);
    short* xf    = (short*)ws;  ws += (size_t)N * NF * sizeof(short);
    short* aggb  = (short*)ws;  ws += (size_t)N * NF * sizeof(short);
    short* Wtab  = (short*)ws;  ws += (size_t)NBLK * (T_TAB + 1) * NF * sizeof(short);
    short* lin1T = (short*)ws;  ws += (size_t)NBLK * NF * HID * sizeof(short);
    short* W2T   = (short*)ws;  ws += (size_t)NBLK * HID * NF * sizeof(short);
    short* W3T   = (short*)ws;  ws += (size_t)NBLK * HID * HID * sizeof(short);
    short* W1Tb  = (short*)ws;  ws += (size_t)NBLK * NF * NF * sizeof(short);
    short* W2Tb  = (short*)ws;  ws += (size_t)NBLK * NF * NF * sizeof(short);
    float* pooledP = (float*)ws; ws += (size_t)NGRAPH * PSLICE * HID * sizeof(float);
    unsigned long long* csr_pk = (unsigned long long*)ws; ws += (size_t)E * sizeof(unsigned long long);
    int* hist    = (int*)ws;  ws += (size_t)N * sizeof(int);
    int* off     = (int*)ws;  ws += (size_t)(N + 1) * sizeof(int);
    int* cursor  = (int*)ws;

    hipMemsetAsync(hist, 0, (size_t)N * sizeof(int), stream);
    hipMemsetAsync(cursor, 0, (size_t)N * sizeof(int), stream);
    hist_k<<<(E + 255) / 256, 256, 0, stream>>>(dst, hist, E);
    scan_k<<<1, 1024, 0, stream>>>(hist, off, N);
    scatter_k<<<(E + 255) / 256, 256, 0, stream>>>(src, dst, edge_len, off,
                                                   cursor, csr_pk, E);
    sort_k<<<(N * 64 + 255) / 256, 256, 0, stream>>>(off, csr_pk, N);

    prep_weights<<<dim3((HID * HID + 255) / 256, NBLK, 5), 256, 0, stream>>>(
        W1s, W1Tb, W2s, W2Tb, lin1Ws, lin1T, lin2Ws, W2T, linWs, W3T);

    build_table_mfma<<<dim3(T_TAB / 32, NBLK), 256, 0, stream>>>(W1Tb, b1s, W2Tb, b2s, Wtab);
    zero_sink<<<NBLK, 128, 0, stream>>>(Wtab);
    embed_k<<<(N * HID + 255) / 256, 256, 0, stream>>>(atom_emb, atom_types, h, N);
    lin1_k<<<(N + 63) / 64, 256, 0, stream>>>(h, lin1T, xf, N);

    for (int i = 0; i < NBLK; ++i) {
        agg_k<<<(N * 64 + 255) / 256, 256, 0, stream>>>(
            xf, Wtab + (size_t)i * (T_TAB + 1) * NF, off, csr_pk, aggb, N);
        update_k<<<(N + 31) / 32, 512, 0, stream>>>(
            aggb, W2T + (size_t)i * HID * NF, lin2bs + (size_t)i * HID,
            W3T + (size_t)i * HID * HID, linbs + (size_t)i * HID, h,
            lin1T + (size_t)(i + 1) * NF * HID,
            (i < NBLK - 1) ? xf : nullptr, N);
    }

    pool_partial<<<dim3(NGRAPH, PSLICE), 256, 0, stream>>>(h, batch_seg, pooledP, N);
    final_mlp<<<NGRAPH, 1024, 0, stream>>>(pooledP, fW1, fb1, fW2, fb2, (float*)d_out);
}

// Round 18
// 513.956 us; speedup vs baseline: 1.0824x; 1.0732x over previous
//
#include <hip/hip_runtime.h>
#include <math.h>

#define HID 256
#define NF 128
#define NGAUSS 100
#define NBLK 6
#define NGRAPH 64
#define CUTOFF_F 10.0f
#define T_TAB 4096
#define PSLICE 8

typedef __attribute__((ext_vector_type(8))) short bf16x8;
typedef __attribute__((ext_vector_type(4))) float f32x4;

__device__ __forceinline__ float ssp(float x) {
    return fmaxf(x, 0.0f) + log1pf(expf(-fabsf(x))) - 0.69314718056f;
}
__device__ __forceinline__ short f2bf(float f) {
    unsigned u = __float_as_uint(f);
    u = u + 0x7fffu + ((u >> 16) & 1u);
    return (short)(u >> 16);
}
__device__ __forceinline__ float bf2f(unsigned s) {
    return __uint_as_float(s << 16);
}

// All 5 weight transposes in one launch: grid.z selects the segment.
__global__ __launch_bounds__(256) void prep_weights(
        const float* __restrict__ W1s,   short* __restrict__ W1Tb,
        const float* __restrict__ W2s,   short* __restrict__ W2Tb,
        const float* __restrict__ lin1Ws, short* __restrict__ lin1T,
        const float* __restrict__ lin2Ws, short* __restrict__ W2T,
        const float* __restrict__ linWs,  short* __restrict__ W3T)
{
    const float* in; short* out; int Ks, Kp, C;
    switch (blockIdx.z) {
        case 0: in = W1s;    out = W1Tb;  Ks = NGAUSS; Kp = NF;  C = NF;  break;
        case 1: in = W2s;    out = W2Tb;  Ks = NF;     Kp = NF;  C = NF;  break;
        case 2: in = lin1Ws; out = lin1T; Ks = HID;    Kp = HID; C = NF;  break;
        case 3: in = lin2Ws; out = W2T;   Ks = NF;     Kp = NF;  C = HID; break;
        default: in = linWs; out = W3T;   Ks = HID;    Kp = HID; C = HID; break;
    }
    int i = blockIdx.y;
    int idx = blockIdx.x * 256 + threadIdx.x;
    if (idx >= Kp * C) return;
    int k = idx / C, c = idx % C;
    out[((size_t)i * C + c) * Kp + k] =
        (k < Ks) ? f2bf(in[((size_t)i * Ks + k) * C + c]) : (short)0;
}

// Wtab[i][t][c] = (ssp(gauss(d_t) @ W1_i + b1_i) @ W2_i + b2_i)[c] via MFMA.
// Layout: [i][(T_TAB+1)][NF]; row T_TAB = zero sink (gated edges), written by block x==0.
__global__ __launch_bounds__(256) void build_table_mfma(
        const short* __restrict__ W1T, const float* __restrict__ b1s,
        const short* __restrict__ W2T, const float* __restrict__ b2s,
        short* __restrict__ Wtab)
{
    __shared__ short Gs[32 * NF];
    __shared__ short Hs[32 * NF];
    char* gb = (char*)Gs;
    char* hb = (char*)Hs;
    const int i = blockIdx.y;
    const int r0 = blockIdx.x * 32;
    const int wv = threadIdx.x >> 6, lane = threadIdx.x & 63;
    const int lrow = lane & 15, lgrp = lane >> 4;

    if (blockIdx.x == 0 && threadIdx.x < NF)
        Wtab[((size_t)i * (T_TAB + 1) + T_TAB) * NF + threadIdx.x] = 0;

    const float delta = CUTOFF_F / 99.0f;
    const float coeff = -0.5f / (delta * delta);
    for (int idx = threadIdx.x; idx < 32 * NF; idx += 256) {
        int row = idx >> 7, k = idx & 127;
        float d = (float)(r0 + row) * (CUTOFF_F / (float)(T_TAB - 1));
        float x = d - (float)k * delta;
        float v = (k < NGAUSS) ? expf(coeff * x * x) : 0.0f;
        int byte = idx * 2;
        byte ^= (row & 7) << 4;
        *(short*)(gb + byte) = f2bf(v);
    }
    __syncthreads();

    f32x4 zero = {0.0f, 0.0f, 0.0f, 0.0f};
    f32x4 c1[2][2] = {{zero, zero}, {zero, zero}};
    for (int s = 0; s < 4; ++s) {
        bf16x8 a[2], b[2];
        #pragma unroll
        for (int m = 0; m < 2; ++m) {
            int row = m * 16 + lrow;
            int byte = (row * NF + s * 32 + lgrp * 8) * 2;
            byte ^= (row & 7) << 4;
            a[m] = *(const bf16x8*)(gb + byte);
        }
        #pragma unroll
        for (int n = 0; n < 2; ++n) {
            int col = wv * 32 + n * 16 + lrow;
            b[n] = *(const bf16x8*)(W1T + ((size_t)i * NF + col) * NF + s * 32 + lgrp * 8);
        }
        #pragma unroll
        for (int m = 0; m < 2; ++m)
            #pragma unroll
            for (int n = 0; n < 2; ++n)
                c1[m][n] = __builtin_amdgcn_mfma_f32_16x16x32_bf16(a[m], b[n], c1[m][n], 0, 0, 0);
    }
    #pragma unroll
    for (int m = 0; m < 2; ++m)
        #pragma unroll
        for (int n = 0; n < 2; ++n) {
            int col = wv * 32 + n * 16 + lrow;
            float bb = b1s[i * NF + col];
            #pragma unroll
            for (int j = 0; j < 4; ++j) {
                int row = m * 16 + lgrp * 4 + j;
                int byte = (row * NF + col) * 2;
                byte ^= (row & 7) << 4;
                *(short*)(hb + byte) = f2bf(ssp(c1[m][n][j] + bb));
            }
        }
    __syncthreads();

    f32x4 c2[2][2] = {{zero, zero}, {zero, zero}};
    for (int s = 0; s < 4; ++s) {
        bf16x8 a[2], b[2];
        #pragma unroll
        for (int m = 0; m < 2; ++m) {
            int row = m * 16 + lrow;
            int byte = (row * NF + s * 32 + lgrp * 8) * 2;
            byte ^= (row & 7) << 4;
            a[m] = *(const bf16x8*)(hb + byte);
        }
        #pragma unroll
        for (int n = 0; n < 2; ++n) {
            int col = wv * 32 + n * 16 + lrow;
            b[n] = *(const bf16x8*)(W2T + ((size_t)i * NF + col) * NF + s * 32 + lgrp * 8);
        }
        #pragma unroll
        for (int m = 0; m < 2; ++m)
            #pragma unroll
            for (int n = 0; n < 2; ++n)
                c2[m][n] = __builtin_amdgcn_mfma_f32_16x16x32_bf16(a[m], b[n], c2[m][n], 0, 0, 0);
    }
    #pragma unroll
    for (int m = 0; m < 2; ++m)
        #pragma unroll
        for (int n = 0; n < 2; ++n) {
            int col = wv * 32 + n * 16 + lrow;
            float bb = b2s[i * NF + col];
            #pragma unroll
            for (int j = 0; j < 4; ++j) {
                int t = r0 + m * 16 + lgrp * 4 + j;
                Wtab[((size_t)i * (T_TAB + 1) + t) * NF + col] = f2bf(c2[m][n][j] + bb);
            }
        }
}

// ---------------- CSR build ----------------
__global__ __launch_bounds__(256) void hist_k(
        const int* __restrict__ dst, int* __restrict__ hist, int E)
{
    int e = blockIdx.x * 256 + threadIdx.x;
    if (e < E) atomicAdd(&hist[dst[e]], 1);
}

__global__ __launch_bounds__(1024) void scan_k(
        const int* __restrict__ in, int* __restrict__ out, int n)
{
    __shared__ int wsum[16];
    __shared__ int carry_s;
    const int tid = threadIdx.x, lane = tid & 63, w = tid >> 6;
    if (tid == 0) carry_s = 0;
    __syncthreads();
    for (int base = 0; base < n; base += 1024) {
        int i = base + tid;
        int v = (i < n) ? in[i] : 0;
        int s = v;
        #pragma unroll
        for (int d = 1; d < 64; d <<= 1) {
            int t = __shfl_up(s, d);
            if (lane >= d) s += t;
        }
        if (lane == 63) wsum[w] = s;
        __syncthreads();
        if (w == 0 && lane < 16) {
            int ws = wsum[lane];
            #pragma unroll
            for (int d = 1; d < 16; d <<= 1) {
                int t = __shfl_up(ws, d);
                if (lane >= d) ws += t;
            }
            wsum[lane] = ws;
        }
        __syncthreads();
        int carry = carry_s;
        if (i < n) out[i] = carry + (w ? wsum[w - 1] : 0) + s - v;
        __syncthreads();
        if (tid == 1023) carry_s = carry + wsum[15];
        __syncthreads();
    }
    if (threadIdx.x == 0) out[n] = carry_s;
}

// packed (i0<<32 | src); i0 = nearest table index; gated edges -> i0 = T_TAB.
__global__ __launch_bounds__(256) void scatter_k(
        const int* __restrict__ src, const int* __restrict__ dst,
        const float* __restrict__ elen, const int* __restrict__ off,
        int* __restrict__ cursor, unsigned long long* __restrict__ csr_pk, int E)
{
    int e = blockIdx.x * 256 + threadIdx.x;
    if (e >= E) return;
    int t = dst[e];
    int pos = off[t] + atomicAdd(&cursor[t], 1);
    float d = elen[e];
    float u = d * ((float)(T_TAB - 1) / CUTOFF_F);
    int i0 = (int)(fminf(fmaxf(u, 0.0f), (float)(T_TAB - 1)) + 0.5f);
    if (i0 > T_TAB - 1) i0 = T_TAB - 1;
    if (d > CUTOFF_F) i0 = T_TAB;   // zero sink
    csr_pk[pos] = ((unsigned long long)(unsigned)i0 << 32) | (unsigned)src[e];
}

// one-time canonical sort of each CSR row -> bit-deterministic accumulation.
__global__ __launch_bounds__(256) void sort_k(
        const int* __restrict__ off, unsigned long long* __restrict__ csr_pk, int N)
{
    const int node = (blockIdx.x * 256 + threadIdx.x) >> 6;
    const int lane = threadIdx.x & 63;
    if (node >= N) return;
    const int beg = off[node], end = off[node + 1];
    const int deg = end - beg;
    if (deg <= 1) return;
    if (deg <= 128) {
        const unsigned long long PAD = ~0ull;
        unsigned long long v0 = (lane < deg) ? csr_pk[beg + lane] : PAD;
        unsigned long long v1 = (64 + lane < deg) ? csr_pk[beg + 64 + lane] : PAD;
        if (deg > 64) {
            for (int size = 2; size <= 128; size <<= 1)
                for (int stride = size >> 1; stride > 0; stride >>= 1) {
                    if (stride == 64) {
                        unsigned long long lo = v0 < v1 ? v0 : v1;
                        unsigned long long hi = v0 < v1 ? v1 : v0;
                        v0 = lo; v1 = hi;
                    } else {
                        unsigned long long p0 = __shfl_xor(v0, stride);
                        unsigned long long p1 = __shfl_xor(v1, stride);
                        bool up = (lane & stride) != 0;
                        bool d0 = ((lane & size) == 0);
                        bool d1 = (((lane + 64) & size) == 0);
                        v0 = (up ^ d0) ? (v0 < p0 ? v0 : p0) : (v0 > p0 ? v0 : p0);
                        v1 = (up ^ d1) ? (v1 < p1 ? v1 : p1) : (v1 > p1 ? v1 : p1);
                    }
                }
            if (lane < deg) csr_pk[beg + lane] = v0;
            if (64 + lane < deg) csr_pk[beg + 64 + lane] = v1;
        } else {
            for (int size = 2; size <= 64; size <<= 1)
                for (int stride = size >> 1; stride > 0; stride >>= 1) {
                    unsigned long long p0 = __shfl_xor(v0, stride);
                    bool up = (lane & stride) != 0;
                    bool d0 = ((lane & size) == 0);
                    v0 = (up ^ d0) ? (v0 < p0 ? v0 : p0) : (v0 > p0 ? v0 : p0);
                }
            if (lane < deg) csr_pk[beg + lane] = v0;
        }
    } else if (lane == 0) {
        for (int a = beg + 1; a < end; ++a) {
            unsigned long long key = csr_pk[a];
            int b = a - 1;
            while (b >= beg && csr_pk[b] > key) { csr_pk[b + 1] = csr_pk[b]; --b; }
            csr_pk[b + 1] = key;
        }
    }
}

// ---------------- per-block kernels ----------------

// Fused embed + lin1: h = emb[types] (fp32) and xf = bf16(h @ lin1W).
// emb is a 100-row table -> L1/L2-resident gathers, no 20 MB h read.
__global__ __launch_bounds__(256) void embed_lin1_k(
        const float* __restrict__ emb, const int* __restrict__ types,
        const short* __restrict__ lin1T, float* __restrict__ h,
        short* __restrict__ xf, int N)
{
    const int wv = threadIdx.x >> 6, lane = threadIdx.x & 63;
    const int lrow = lane & 15, lgrp = lane >> 4;
    const int wrow = wv >> 1, wcol = wv & 1;
    const int r0 = blockIdx.x * 64 + wrow * 32;

    // h init: coalesced float4 writes, emb gather (L2)
    for (int idx = threadIdx.x; idx < 64 * (HID / 4); idx += 256) {
        int row = blockIdx.x * 64 + (idx >> 6);
        int c4 = idx & 63;
        if (row < N) {
            int t = types[row];
            ((float4*)(h + (size_t)row * HID))[c4] =
                ((const float4*)(emb + (size_t)t * HID))[c4];
        }
    }

    f32x4 zero = {0.0f, 0.0f, 0.0f, 0.0f};
    f32x4 c[2][4] = {{zero, zero, zero, zero}, {zero, zero, zero, zero}};

    for (int s = 0; s < 8; ++s) {
        bf16x8 a[2], b[4];
        #pragma unroll
        for (int m = 0; m < 2; ++m) {
            int row = r0 + m * 16 + lrow;
            if (row >= N) row = N - 1;
            const float* hp = emb + (size_t)types[row] * HID + s * 32 + lgrp * 8;
            float4 p0 = *(const float4*)hp;
            float4 p1 = *(const float4*)(hp + 4);
            bf16x8 t;
            t[0] = f2bf(p0.x); t[1] = f2bf(p0.y); t[2] = f2bf(p0.z); t[3] = f2bf(p0.w);
            t[4] = f2bf(p1.x); t[5] = f2bf(p1.y); t[6] = f2bf(p1.z); t[7] = f2bf(p1.w);
            a[m] = t;
        }
        #pragma unroll
        for (int n = 0; n < 4; ++n) {
            int col = wcol * 64 + n * 16 + lrow;
            b[n] = *(const bf16x8*)(lin1T + (size_t)col * HID + s * 32 + lgrp * 8);
        }
        #pragma unroll
        for (int m = 0; m < 2; ++m)
            #pragma unroll
            for (int n = 0; n < 4; ++n)
                c[m][n] = __builtin_amdgcn_mfma_f32_16x16x32_bf16(a[m], b[n], c[m][n], 0, 0, 0);
    }
    #pragma unroll
    for (int m = 0; m < 2; ++m)
        #pragma unroll
        for (int n = 0; n < 4; ++n) {
            int col = wcol * 64 + n * 16 + lrow;
            #pragma unroll
            for (int j = 0; j < 4; ++j) {
                int row = r0 + m * 16 + lgrp * 4 + j;
                if (row < N) xf[(size_t)row * NF + col] = f2bf(c[m][n][j]);
            }
        }
}

// one wave per dst node; sorted keys carry precomputed nearest table index ->
// per edge: 2 loads + 4 unpacks + 2 FMA. 8-wide gather groups.
__global__ __launch_bounds__(256) void agg_k(
        const short* __restrict__ xf, const short* __restrict__ wt,
        const int* __restrict__ off, const unsigned long long* __restrict__ csr_pk,
        short* __restrict__ agg, int N)
{
    const int node = (blockIdx.x * 256 + threadIdx.x) >> 6;
    const int lane = threadIdx.x & 63;
    if (node >= N) return;
    const int beg = __builtin_amdgcn_readfirstlane(off[node]);
    const int end = __builtin_amdgcn_readfirstlane(off[node + 1]);
    float a0 = 0.0f, a1 = 0.0f;

    int k = beg;
    for (; k + 8 <= end; k += 8) {
        unsigned long long pk[8];
        #pragma unroll
        for (int q = 0; q < 8; ++q) pk[q] = csr_pk[k + q];
        unsigned wv[8], xv[8];
        #pragma unroll
        for (int q = 0; q < 8; ++q) {
            int i0 = (int)(pk[q] >> 32);
            int s  = (int)(unsigned)pk[q];
            wv[q] = *(const unsigned*)(wt + (size_t)i0 * NF + 2 * lane);
            xv[q] = *(const unsigned*)(xf + (size_t)s * NF + 2 * lane);
        }
        #pragma unroll
        for (int q = 0; q < 8; ++q) {
            float wa = bf2f(wv[q] & 0xffffu), wb = bf2f(wv[q] >> 16);
            float xa = bf2f(xv[q] & 0xffffu), xb = bf2f(xv[q] >> 16);
            a0 = fmaf(xa, wa, a0);
            a1 = fmaf(xb, wb, a1);
        }
    }
    if (k < end) {
        const int rem = end - k;
        unsigned long long pk[8];
        #pragma unroll
        for (int q = 0; q < 8; ++q) {
            int kk = k + q < end ? k + q : end - 1;
            pk[q] = csr_pk[kk];
        }
        unsigned wv[8], xv[8];
        #pragma unroll
        for (int q = 0; q < 8; ++q) {
            int i0 = (int)(pk[q] >> 32);
            int s  = (int)(unsigned)pk[q];
            wv[q] = *(const unsigned*)(wt + (size_t)i0 * NF + 2 * lane);
            xv[q] = *(const unsigned*)(xf + (size_t)s * NF + 2 * lane);
        }
        #pragma unroll
        for (int q = 0; q < 8; ++q) {
            float g = (q < rem) ? 1.0f : 0.0f;
            float wa = bf2f(wv[q] & 0xffffu), wb = bf2f(wv[q] >> 16);
            float xa = bf2f(xv[q] & 0xffffu), xb = bf2f(xv[q] >> 16);
            a0 = fmaf(xa * g, wa, a0);
            a1 = fmaf(xb * g, wb, a1);
        }
    }
    unsigned pack = (unsigned)(unsigned short)f2bf(a0)
                  | ((unsigned)(unsigned short)f2bf(a1) << 16);
    *(unsigned*)(agg + (size_t)node * NF + 2 * lane) = pack;
}

// h += (ssp(agg@lin2W+b2) @ linW + b3); optionally xf_next = bf16(h_new @ lin1W_next)
// 512 threads / 8 waves: 32 cols per wave.
__global__ __launch_bounds__(512) void update_k(
        const short* __restrict__ aggb, const short* __restrict__ W2T,
        const float* __restrict__ b2, const short* __restrict__ W3T,
        const float* __restrict__ b3, float* __restrict__ h,
        const short* __restrict__ lin1Tn, short* __restrict__ xf_out, int N)
{
    __shared__ short tmp[32 * HID];      // 16 KB bf16, XOR-swizzled rows
    __shared__ float ftmp[32][HID + 4];  // 33 KB fp32, padded
    char* tb = (char*)tmp;
    const int wv = threadIdx.x >> 6, lane = threadIdx.x & 63;
    const int lrow = lane & 15, lgrp = lane >> 4;
    const int r0 = blockIdx.x * 32;

    f32x4 zero = {0.0f, 0.0f, 0.0f, 0.0f};
    f32x4 c1[2][2] = {{zero, zero}, {zero, zero}};

    // matmul1: [32 x 128] @ [128 x 256]
    for (int s = 0; s < 4; ++s) {
        bf16x8 a[2], b[2];
        #pragma unroll
        for (int m = 0; m < 2; ++m) {
            int row = r0 + m * 16 + lrow;
            if (row >= N) row = N - 1;
            a[m] = *(const bf16x8*)(aggb + (size_t)row * NF + s * 32 + lgrp * 8);
        }
        #pragma unroll
        for (int n = 0; n < 2; ++n) {
            int col = wv * 32 + n * 16 + lrow;
            b[n] = *(const bf16x8*)(W2T + (size_t)col * NF + s * 32 + lgrp * 8);
        }
        #pragma unroll
        for (int m = 0; m < 2; ++m)
            #pragma unroll
            for (int n = 0; n < 2; ++n)
                c1[m][n] = __builtin_amdgcn_mfma_f32_16x16x32_bf16(a[m], b[n], c1[m][n], 0, 0, 0);
    }
    #pragma unroll
    for (int m = 0; m < 2; ++m)
        #pragma unroll
        for (int n = 0; n < 2; ++n) {
            int col = wv * 32 + n * 16 + lrow;
            float bb = b2[col];
            #pragma unroll
            for (int j = 0; j < 4; ++j) {
                int row = m * 16 + lgrp * 4 + j;
                int byte = (row * HID + col) * 2;
                byte ^= (row & 7) << 4;
                *(short*)(tb + byte) = f2bf(ssp(c1[m][n][j] + bb));
            }
        }
    __syncthreads();

    f32x4 c2[2][2] = {{zero, zero}, {zero, zero}};
    // matmul2: [32 x 256] @ [256 x 256]
    for (int s = 0; s < 8; ++s) {
        bf16x8 a[2], b[2];
        #pragma unroll
        for (int m = 0; m < 2; ++m) {
            int row = m * 16 + lrow;
            int byte = (row * HID + s * 32 + lgrp * 8) * 2;
            byte ^= (row & 7) << 4;
            a[m] = *(const bf16x8*)(tb + byte);
        }
        #pragma unroll
        for (int n = 0; n < 2; ++n) {
            int col = wv * 32 + n * 16 + lrow;
            b[n] = *(const bf16x8*)(W3T + (size_t)col * HID + s * 32 + lgrp * 8);
        }
        #pragma unroll
        for (int m = 0; m < 2; ++m)
            #pragma unroll
            for (int n = 0; n < 2; ++n)
                c2[m][n] = __builtin_amdgcn_mfma_f32_16x16x32_bf16(a[m], b[n], c2[m][n], 0, 0, 0);
    }

    #pragma unroll
    for (int m = 0; m < 2; ++m)
        #pragma unroll
        for (int n = 0; n < 2; ++n) {
            int col = wv * 32 + n * 16 + lrow;
            float bb = b3[col];
            #pragma unroll
            for (int j = 0; j < 4; ++j)
                ftmp[m * 16 + lgrp * 4 + j][col] = c2[m][n][j] + bb;
        }
    __syncthreads();   // ftmp ready AND matmul2's tmp reads complete

    // coalesced h RMW + bf16(h_new) into swizzled tmp
    {
        const int r  = threadIdx.x >> 4;         // 0..31
        const int c0 = (threadIdx.x & 15) * 4;   // 0..60
        const int row = r0 + r;
        const bool valid = row < N;
        float* hp = h + (size_t)row * HID;
        #pragma unroll
        for (int k = 0; k < 4; ++k) {
            int col = c0 + k * 64;
            float4 hv = valid ? *(const float4*)(hp + col)
                              : make_float4(0.f, 0.f, 0.f, 0.f);
            float4 f = *(const float4*)&ftmp[r][col];
            hv.x += f.x; hv.y += f.y; hv.z += f.z; hv.w += f.w;
            if (valid) *(float4*)(hp + col) = hv;
            short4 s4;
            s4.x = f2bf(hv.x); s4.y = f2bf(hv.y); s4.z = f2bf(hv.z); s4.w = f2bf(hv.w);
            int byte = (r * HID + col) * 2;
            byte ^= (r & 7) << 4;
            *(short4*)(tb + byte) = s4;
        }
    }
    if (xf_out == nullptr) return;
    __syncthreads();

    // stage 3: xf_next = h_new @ lin1W_next   [32 x 256] @ [256 x 128]
    f32x4 c3[2] = {zero, zero};
    for (int s = 0; s < 8; ++s) {
        bf16x8 a[2], b;
        #pragma unroll
        for (int m = 0; m < 2; ++m) {
            int row = m * 16 + lrow;
            int byte = (row * HID + s * 32 + lgrp * 8) * 2;
            byte ^= (row & 7) << 4;
            a[m] = *(const bf16x8*)(tb + byte);
        }
        {
            int col = wv * 16 + lrow;
            b = *(const bf16x8*)(lin1Tn + (size_t)col * HID + s * 32 + lgrp * 8);
        }
        #pragma unroll
        for (int m = 0; m < 2; ++m)
            c3[m] = __builtin_amdgcn_mfma_f32_16x16x32_bf16(a[m], b, c3[m], 0, 0, 0);
    }
    #pragma unroll
    for (int m = 0; m < 2; ++m) {
        int col = wv * 16 + lrow;
        #pragma unroll
        for (int j = 0; j < 4; ++j) {
            int row = r0 + m * 16 + lgrp * 4 + j;
            if (row < N) xf_out[(size_t)row * NF + col] = f2bf(c3[m][j]);
        }
    }
}

// Stage 1: partial max. grid (NGRAPH, PSLICE); fixed slices, serial order.
__global__ __launch_bounds__(256) void pool_partial(
        const float* __restrict__ h, const int* __restrict__ seg,
        float* __restrict__ pooledP, int N)
{
    const int g = blockIdx.x, sl = blockIdx.y, c = threadIdx.x;
    int lo, hi;
    {
        int a = 0, b = N;
        while (a < b) { int m = (a + b) >> 1; if (seg[m] < g) a = m + 1; else b = m; }
        lo = a;
        b = N;
        while (a < b) { int m = (a + b) >> 1; if (seg[m] < g + 1) a = m + 1; else b = m; }
        hi = a;
    }
    const int len = hi - lo;
    const int chunk = (len + PSLICE - 1) / PSLICE;
    const int s0 = lo + sl * chunk;
    const int s1 = min(s0 + chunk, hi);

    float m0 = -INFINITY, m1 = -INFINITY, m2 = -INFINITY, m3 = -INFINITY;
    int r = s0;
    for (; r + 4 <= s1; r += 4) {
        m0 = fmaxf(m0, h[(size_t)(r    ) * HID + c]);
        m1 = fmaxf(m1, h[(size_t)(r + 1) * HID + c]);
        m2 = fmaxf(m2, h[(size_t)(r + 2) * HID + c]);
        m3 = fmaxf(m3, h[(size_t)(r + 3) * HID + c]);
    }
    for (; r < s1; ++r) m0 = fmaxf(m0, h[(size_t)r * HID + c]);
    pooledP[((size_t)g * PSLICE + sl) * HID + c] = fmaxf(fmaxf(m0, m1), fmaxf(m2, m3));
}

// Stage 2: reduce partials (fixed order) + 2-layer MLP, k-split x4.
__global__ __launch_bounds__(1024) void final_mlp(
        const float* __restrict__ pooledP,
        const float* __restrict__ fW1, const float* __restrict__ fb1,
        const float* __restrict__ fW2, const float* __restrict__ fb2,
        float* __restrict__ out)
{
    __shared__ float p[HID];
    __shared__ float part[4][HID];
    __shared__ float p2[HID];
    const int g = blockIdx.x;
    const int c = threadIdx.x & 255;
    const int kq = threadIdx.x >> 8;
    if (threadIdx.x < HID) {
        float m = -INFINITY;
        #pragma unroll
        for (int s = 0; s < PSLICE; ++s)
            m = fmaxf(m, pooledP[((size_t)g * PSLICE + s) * HID + threadIdx.x]);
        p[threadIdx.x] = m;
    }
    __syncthreads();
    float a = 0.0f;
    #pragma unroll 8
    for (int k = kq * 64; k < kq * 64 + 64; ++k)
        a = fmaf(p[k], fW1[(size_t)k * HID + c], a);
    part[kq][c] = a;
    __syncthreads();
    if (kq == 0) {
        float s = part[0][c] + part[1][c] + part[2][c] + part[3][c] + fb1[c];
        p2[c] = fmaxf(s, 0.0f);
    }
    __syncthreads();
    float o = 0.0f;
    #pragma unroll 8
    for (int k = kq * 64; k < kq * 64 + 64; ++k)
        o = fmaf(p2[k], fW2[(size_t)k * HID + c], o);
    part[kq][c] = o;
    __syncthreads();
    if (kq == 0)
        out[(size_t)g * HID + c] = part[0][c] + part[1][c] + part[2][c] + part[3][c] + fb2[c];
}

extern "C" void kernel_launch(void* const* d_in, const int* in_sizes, int n_in,
                              void* d_out, int out_size, void* d_ws, size_t ws_size,
                              hipStream_t stream)
{
    const int*   atom_types = (const int*)  d_in[0];
    const int*   edge_index = (const int*)  d_in[1];
    const float* edge_len   = (const float*)d_in[2];
    const int*   batch_seg  = (const int*)  d_in[3];
    const float* atom_emb   = (const float*)d_in[4];
    const float* W1s    = (const float*)d_in[5];
    const float* b1s    = (const float*)d_in[6];
    const float* W2s    = (const float*)d_in[7];
    const float* b2s    = (const float*)d_in[8];
    const float* lin1Ws = (const float*)d_in[9];
    const float* lin2Ws = (const float*)d_in[10];
    const float* lin2bs = (const float*)d_in[11];
    const float* linWs  = (const float*)d_in[12];
    const float* linbs  = (const float*)d_in[13];
    const float* fW1    = (const float*)d_in[14];
    const float* fb1    = (const float*)d_in[15];
    const float* fW2    = (const float*)d_in[16];
    const float* fb2    = (const float*)d_in[17];

    const int N = in_sizes[0];
    const int E = in_sizes[1] / 2;
    const int* src = edge_index;
    const int* dst = edge_index + E;

    char* ws = (char*)d_ws;
    float* h     = (float*)ws;  ws += (size_t)N * HID * sizeof(float);
    short* xf    = (short*)ws;  ws += (size_t)N * NF * sizeof(short);
    short* aggb  = (short*)ws;  ws += (size_t)N * NF * sizeof(short);
    short* Wtab  = (short*)ws;  ws += (size_t)NBLK * (T_TAB + 1) * NF * sizeof(short);
    short* lin1T = (short*)ws;  ws += (size_t)NBLK * NF * HID * sizeof(short);
    short* W2T   = (short*)ws;  ws += (size_t)NBLK * HID * NF * sizeof(short);
    short* W3T   = (short*)ws;  ws += (size_t)NBLK * HID * HID * sizeof(short);
    short* W1Tb  = (short*)ws;  ws += (size_t)NBLK * NF * NF * sizeof(short);
    short* W2Tb  = (short*)ws;  ws += (size_t)NBLK * NF * NF * sizeof(short);
    float* pooledP = (float*)ws; ws += (size_t)NGRAPH * PSLICE * HID * sizeof(float);
    unsigned long long* csr_pk = (unsigned long long*)ws; ws += (size_t)E * sizeof(unsigned long long);
    int* hist    = (int*)ws;  ws += (size_t)N * sizeof(int);
    int* off     = (int*)ws;  ws += (size_t)(N + 1) * sizeof(int);
    int* cursor  = (int*)ws;

    hipMemsetAsync(hist, 0, (size_t)N * sizeof(int), stream);
    hipMemsetAsync(cursor, 0, (size_t)N * sizeof(int), stream);
    hist_k<<<(E + 255) / 256, 256, 0, stream>>>(dst, hist, E);
    scan_k<<<1, 1024, 0, stream>>>(hist, off, N);
    scatter_k<<<(E + 255) / 256, 256, 0, stream>>>(src, dst, edge_len, off,
                                                   cursor, csr_pk, E);
    sort_k<<<(N * 64 + 255) / 256, 256, 0, stream>>>(off, csr_pk, N);

    prep_weights<<<dim3((HID * HID + 255) / 256, NBLK, 5), 256, 0, stream>>>(
        W1s, W1Tb, W2s, W2Tb, lin1Ws, lin1T, lin2Ws, W2T, linWs, W3T);

    build_table_mfma<<<dim3(T_TAB / 32, NBLK), 256, 0, stream>>>(W1Tb, b1s, W2Tb, b2s, Wtab);
    embed_lin1_k<<<(N + 63) / 64, 256, 0, stream>>>(atom_emb, atom_types, lin1T, h, xf, N);

    for (int i = 0; i < NBLK; ++i) {
        agg_k<<<(N * 64 + 255) / 256, 256, 0, stream>>>(
            xf, Wtab + (size_t)i * (T_TAB + 1) * NF, off, csr_pk, aggb, N);
        update_k<<<(N + 31) / 32, 512, 0, stream>>>(
            aggb, W2T + (size_t)i * HID * NF, lin2bs + (size_t)i * HID,
            W3T + (size_t)i * HID * HID, linbs + (size_t)i * HID, h,
            lin1T + (size_t)(i + 1) * NF * HID,
            (i < NBLK - 1) ? xf : nullptr, N);
    }

    pool_partial<<<dim3(NGRAPH, PSLICE), 256, 0, stream>>>(h, batch_seg, pooledP, N);
    final_mlp<<<NGRAPH, 1024, 0, stream>>>(pooledP, fW1, fb1, fW2, fb2, (float*)d_out);
}